// Round 1
// baseline (1247.726 us; speedup 1.0000x reference)
//
#include <hip/hip_runtime.h>
#include <math.h>

#define SS 128
#define BB 32
#define CC 16
#define DW 256
#define DC 64
#define HC 128
#define KX 384   // DW + HC
#define TT 17

typedef __attribute__((ext_vector_type(8))) short bf16x8;
typedef __attribute__((ext_vector_type(4))) float f32x4;
typedef unsigned long long ull_t;

__device__ __forceinline__ float sigf(float x) { return 1.0f / (1.0f + __expf(-x)); }
__device__ __forceinline__ float tanhfast(float x) {
  float xc = fminf(fmaxf(x, -15.f), 15.f);
  float e = __expf(2.f * xc);
  return (e - 1.f) / (e + 1.f);
}
__device__ __forceinline__ unsigned short f2bf(float x) {
  unsigned int u = __float_as_uint(x);
  u += 0x7FFF + ((u >> 16) & 1);
  return (unsigned short)(u >> 16);
}
// Relaxed agent-scope atomics ONLY (native 32/64-bit, cache-bypassing; no fences).
__device__ __forceinline__ void st_u32(unsigned* p, unsigned v) {
  __hip_atomic_store(p, v, __ATOMIC_RELAXED, __HIP_MEMORY_SCOPE_AGENT);
}
__device__ __forceinline__ ull_t ld_ull(const ull_t* p) {
  return __hip_atomic_load(p, __ATOMIC_RELAXED, __HIP_MEMORY_SCOPE_AGENT);
}

// ---------------------------------------------------------------- K0: char ih vocab table
__global__ __launch_bounds__(256) void k0_ihvocab(
    const float* __restrict__ Wce,
    const float* __restrict__ WihF, const float* __restrict__ bF,
    const float* __restrict__ WihB, const float* __restrict__ bB,
    float* __restrict__ ihv) {
  int blk = blockIdx.x;          // 0..199
  int d = blk / 100, v = blk % 100;
  const float* Wih = d ? WihB : WihF;
  const float* bb  = d ? bB   : bF;
  __shared__ float ce[DC];
  if (threadIdx.x < DC) ce[threadIdx.x] = Wce[v * DC + threadIdx.x];
  __syncthreads();
  int g = threadIdx.x;
  float acc = bb[g];
  #pragma unroll 16
  for (int k = 0; k < DC; ++k) acc += ce[k] * Wih[g * DC + k];
  ihv[(d * 100 + v) * 256 + g] = acc;
}

// ---------------------------------------------------------------- K1: char BiLSTM (per-chain, no global sync)
__global__ __launch_bounds__(256) void k1_char(
    const int* __restrict__ charidx,   // (B,S,C)
    const float* __restrict__ WhhF, const float* __restrict__ WhhB,
    const float* __restrict__ ihv,     // (2,100,256)
    float* __restrict__ x)             // (4096, 384)
{
  int blk = blockIdx.x;
  int d = blk >> 8;
  int n0 = (blk & 255) * 16;
  const float* Whh = d ? WhhB : WhhF;

  __shared__ float Wl[256 * 68];
  __shared__ float hl[16 * 68];

  for (int i = threadIdx.x; i < 256 * 64; i += 256) {
    int g = i >> 6, k = i & 63;
    Wl[g * 68 + k] = Whh[i];
  }
  __syncthreads();

  int hh = threadIdx.x & 63;
  int ng = threadIdx.x >> 6;
  float c[4] = {0.f, 0.f, 0.f, 0.f};
  float h[4] = {0.f, 0.f, 0.f, 0.f};
  int bb_[4], ss_[4];
  #pragma unroll
  for (int m = 0; m < 4; ++m) {
    int n = n0 + ng + 4 * m;
    bb_[m] = n >> 7; ss_[m] = n & 127;
  }

  for (int t = 0; t < CC; ++t) {
    int cpos = d ? (CC - 1 - t) : t;
    float acc[4][4];
    #pragma unroll
    for (int m = 0; m < 4; ++m) {
      int v = charidx[bb_[m] * (SS * CC) + ss_[m] * CC + cpos];
      const float* base = ihv + (d * 100 + v) * 256 + hh;
      acc[m][0] = base[0]; acc[m][1] = base[64]; acc[m][2] = base[128]; acc[m][3] = base[192];
    }
    if (t > 0) {
      #pragma unroll 4
      for (int k = 0; k < 64; k += 4) {
        float4 w4[4];
        #pragma unroll
        for (int q = 0; q < 4; ++q)
          w4[q] = *(const float4*)&Wl[(q * 64 + hh) * 68 + k];
        #pragma unroll
        for (int m = 0; m < 4; ++m) {
          float4 h4 = *(const float4*)&hl[(ng + 4 * m) * 68 + k];
          #pragma unroll
          for (int q = 0; q < 4; ++q)
            acc[m][q] += h4.x * w4[q].x + h4.y * w4[q].y + h4.z * w4[q].z + h4.w * w4[q].w;
        }
      }
      __syncthreads();
    }
    #pragma unroll
    for (int m = 0; m < 4; ++m) {
      float ig = sigf(acc[m][0]);
      float fg = sigf(acc[m][1]);
      float gg = tanhfast(acc[m][2]);
      float og = sigf(acc[m][3]);
      c[m] = fg * c[m] + ig * gg;
      h[m] = og * tanhfast(c[m]);
      hl[(ng + 4 * m) * 68 + hh] = h[m];
    }
    __syncthreads();
  }
  #pragma unroll
  for (int m = 0; m < 4; ++m) {
    int row = ss_[m] * BB + bb_[m];
    x[row * KX + d * 64 + hh] = h[m];
  }
}

// ---------------------------------------------------------------- K2: word embedding gather
__global__ __launch_bounds__(64) void k2_we(
    const int* __restrict__ sentence, const float* __restrict__ Wwe,
    float* __restrict__ x) {
  int row = blockIdx.x;
  int idx = sentence[row];
  const float4* src = (const float4*)(Wwe + (size_t)idx * DW);
  float4* dst = (float4*)(x + (size_t)row * KX + HC);
  dst[threadIdx.x] = src[threadIdx.x];
}

// ---------------------------------------------------------------- K3: word ih GEMM  wg[d][row][g]
__global__ __launch_bounds__(256) void k3_ihgemm(
    const float* __restrict__ x,
    const float* __restrict__ WihF, const float* __restrict__ bF,
    const float* __restrict__ WihB, const float* __restrict__ bB,
    float* __restrict__ wg) {
  int n0 = blockIdx.x * 128;
  int m0 = blockIdx.y * 128;
  int d  = n0 >> 10;
  int gb = n0 & 1023;
  const float* Wih  = d ? WihB : WihF;
  const float* bias = d ? bB   : bF;

  __shared__ float At[32][132];
  __shared__ float Bt[32][132];

  int tid = threadIdx.x;
  int half = tid & 1, r = tid >> 1;
  int tm = tid & 15, tn = tid >> 4;
  float acc[8][8] = {};

  for (int k0 = 0; k0 < KX; k0 += 32) {
    __syncthreads();
    {
      const float4* srcA = (const float4*)(x + (size_t)(m0 + r) * KX + k0 + half * 16);
      const float4* srcB = (const float4*)(Wih + (size_t)(gb + r) * KX + k0 + half * 16);
      #pragma unroll
      for (int q = 0; q < 4; ++q) {
        float4 v = srcA[q];
        int kk = half * 16 + q * 4;
        At[kk + 0][r] = v.x; At[kk + 1][r] = v.y; At[kk + 2][r] = v.z; At[kk + 3][r] = v.w;
      }
      #pragma unroll
      for (int q = 0; q < 4; ++q) {
        float4 v = srcB[q];
        int kk = half * 16 + q * 4;
        Bt[kk + 0][r] = v.x; Bt[kk + 1][r] = v.y; Bt[kk + 2][r] = v.z; Bt[kk + 3][r] = v.w;
      }
    }
    __syncthreads();
    #pragma unroll 8
    for (int k = 0; k < 32; ++k) {
      float4 a0 = *(const float4*)&At[k][tm * 8];
      float4 a1 = *(const float4*)&At[k][tm * 8 + 4];
      float4 b0 = *(const float4*)&Bt[k][tn * 8];
      float4 b1 = *(const float4*)&Bt[k][tn * 8 + 4];
      float av[8] = {a0.x, a0.y, a0.z, a0.w, a1.x, a1.y, a1.z, a1.w};
      float bv[8] = {b0.x, b0.y, b0.z, b0.w, b1.x, b1.y, b1.z, b1.w};
      #pragma unroll
      for (int i = 0; i < 8; ++i)
        #pragma unroll
        for (int jq = 0; jq < 8; ++jq)
          acc[i][jq] += av[i] * bv[jq];
    }
  }
  float bv8[8];
  #pragma unroll
  for (int jq = 0; jq < 8; ++jq) bv8[jq] = bias[gb + tn * 8 + jq];
  #pragma unroll
  for (int i = 0; i < 8; ++i) {
    int m = m0 + tm * 8 + i;
    float* dst = wg + ((size_t)(d * 4096 + m)) * 1024 + gb + tn * 8;
    float4 v0 = {acc[i][0] + bv8[0], acc[i][1] + bv8[1], acc[i][2] + bv8[2], acc[i][3] + bv8[3]};
    float4 v1 = {acc[i][4] + bv8[4], acc[i][5] + bv8[5], acc[i][6] + bv8[6], acc[i][7] + bv8[7]};
    *(float4*)dst = v0; *(float4*)(dst + 4) = v1;
  }
}

// ---------------------------------------------------------------- K4: word BiLSTM recurrence
// 32 WGs x 64 threads (1 wave each), 16 waves per direction. Wave widx owns
// h-cols j0w..j0w+15 (x4 gate blocks). Whh in 128 VGPRs as bf16 B-frags.
// Handshake: SELF-TAGGED data words. Each published h element is a u32:
//   (step_tag=t+1)<<16 | bf16(h).  Producer fires 8 relaxed tagged stores
// (no vmcnt drain, no flag). Consumer's poll IS the data load: re-issue the
// 64 ld_ull until all embedded tags == t; values are then already in regs.
// 2-slot parity buffer gives the one-step slack (classic induction: no wave
// can publish h_{t+1} before every wave consumed h_{t-1}); inter-step store
// ordering to the same address is enforced because a wave's step-t stores
// are OBSERVED at the coherence point (own poll at t+1) before it can issue
// step-t+2 stores. hbuf is memset(0) each launch -> stale tags never match.
__global__ __launch_bounds__(64, 1) void k4_word(
    const float* __restrict__ WhhF, const float* __restrict__ WhhB,
    const float* __restrict__ wg,           // (2,4096,1024) f32
    float* __restrict__ outh,               // (4096,512) f32
    unsigned int* __restrict__ hbuf) {      // (2 dir, 2 parity, 32 b, 256 k) tagged u32
  const int blk = blockIdx.x;               // 0..31
  const int d = blk >> 4, widx = blk & 15;
  const int l = threadIdx.x;                // 0..63
  const int l15 = l & 15, q4 = l >> 4;
  const int j0w = widx * 16;
  const float* __restrict__ Whh = d ? WhhB : WhhF;
  unsigned int* hb_d = hbuf + d * 16384;    // 2 parities * 8192 u32

  // ---- Whh B-fragments resident: lane holds B[k=ks*32+q4*8+j][n=l15]
  bf16x8 Bf[4][8];
  #pragma unroll
  for (int q = 0; q < 4; ++q) {
    const float* wr = Whh + (size_t)(q * 256 + j0w + l15) * 256 + q4 * 8;
    #pragma unroll
    for (int ks = 0; ks < 8; ++ks) {
      float4 lo = *(const float4*)(wr + ks * 32);
      float4 hi = *(const float4*)(wr + ks * 32 + 4);
      bf16x8 f;
      f[0] = (short)f2bf(lo.x); f[1] = (short)f2bf(lo.y);
      f[2] = (short)f2bf(lo.z); f[3] = (short)f2bf(lo.w);
      f[4] = (short)f2bf(hi.x); f[5] = (short)f2bf(hi.y);
      f[6] = (short)f2bf(hi.z); f[7] = (short)f2bf(hi.w);
      Bf[q][ks] = f;
    }
  }

  float cst[8];
  #pragma unroll
  for (int i = 0; i < 8; ++i) cst[i] = 0.f;

  for (int t = 0; t < SS; ++t) {
    const int s = d ? (SS - 1 - t) : t;

    // ---- ih gates into MFMA C-layout (issued before the poll; overlaps it)
    f32x4 acc[4][2];
    const float* wgs = wg + ((size_t)d * 4096 + (size_t)s * 32) * 1024 + j0w + l15;
    #pragma unroll
    for (int q = 0; q < 4; ++q)
      #pragma unroll
      for (int mt = 0; mt < 2; ++mt)
        #pragma unroll
        for (int r = 0; r < 4; ++r)
          acc[q][mt][r] = wgs[(size_t)(q4 * 4 + r + mt * 16) * 1024 + q * 256];

    if (t > 0) {
      // ---- poll = load: tagged A-fragments of h_{t-1}
      const unsigned int* hp = hb_d + ((t - 1) & 1) * 8192;
      const ull_t want2 = ((ull_t)(unsigned)t << 16) | ((ull_t)(unsigned)t << 48);
      bf16x8 Af[2][8];
      for (;;) {
        ull_t bad = 0;
        #pragma unroll
        for (int mt = 0; mt < 2; ++mt) {
          const ull_t* rp = (const ull_t*)(hp + (size_t)(l15 + mt * 16) * 256) + q4 * 4;
          #pragma unroll
          for (int ks = 0; ks < 8; ++ks) {
            union { unsigned int u[4]; bf16x8 v; } cv;
            #pragma unroll
            for (int p = 0; p < 4; ++p) {
              ull_t w = ld_ull(rp + ks * 16 + p);
              bad |= (w ^ want2) & 0xffff0000ffff0000ull;
              cv.u[p] = (unsigned)((w & 0xffffull) | ((w >> 16) & 0xffff0000ull));
            }
            Af[mt][ks] = cv.v;
          }
        }
        if (__all(bad == 0)) break;
      }
      #pragma unroll
      for (int q = 0; q < 4; ++q)
        #pragma unroll
        for (int mt = 0; mt < 2; ++mt) {
          f32x4 c = acc[q][mt];
          #pragma unroll
          for (int ks = 0; ks < 8; ++ks)
            c = __builtin_amdgcn_mfma_f32_16x16x32_bf16(Af[mt][ks], Bf[q][ks], c, 0, 0, 0);
          acc[q][mt] = c;
        }
    }

    // ---- activations; lane owns (b = q4*4+r+mt*16, col = j0w+l15)
    float hv[8];
    #pragma unroll
    for (int mt = 0; mt < 2; ++mt)
      #pragma unroll
      for (int r = 0; r < 4; ++r) {
        int ix = mt * 4 + r;
        float ig = sigf(acc[0][mt][r]);
        float fg = sigf(acc[1][mt][r]);
        float gg = tanhfast(acc[2][mt][r]);
        float og = sigf(acc[3][mt][r]);
        float c2 = fg * cst[ix] + ig * gg;
        cst[ix] = c2;
        hv[ix] = og * tanhfast(c2);
      }

    // ---- publish: 8 tagged u32 scatter stores (4x64B segments each; no
    //      drain, no flag, no LDS). Stores flow out while we continue.
    {
      unsigned int tagv = ((unsigned)(t + 1)) << 16;
      unsigned int* wp = hb_d + (t & 1) * 8192;
      #pragma unroll
      for (int mt = 0; mt < 2; ++mt)
        #pragma unroll
        for (int r = 0; r < 4; ++r) {
          int row = q4 * 4 + r + mt * 16;
          st_u32(wp + (size_t)row * 256 + j0w + l15,
                 tagv | (unsigned)f2bf(hv[mt * 4 + r]));
        }
    }

    // ---- outh (non-temporal, off critical path)
    float* op = outh + (size_t)(s * 32) * 512 + d * 256 + j0w + l15;
    #pragma unroll
    for (int mt = 0; mt < 2; ++mt)
      #pragma unroll
      for (int r = 0; r < 4; ++r)
        __builtin_nontemporal_store(hv[mt * 4 + r], op + (size_t)(q4 * 4 + r + mt * 16) * 512);
  }
}

// ---------------------------------------------------------------- K5: emit GEMM (tiny)
__global__ __launch_bounds__(64) void k5_emit(
    const float* __restrict__ outh, const float* __restrict__ eW,
    const float* __restrict__ eb, float* __restrict__ em) {
  int row = blockIdx.x;
  int t = threadIdx.x;
  if (t < TT) {
    const float4* o4 = (const float4*)(outh + (size_t)row * 512);
    const float4* w4 = (const float4*)(eW + (size_t)t * 512);
    float acc = 0.f;
    #pragma unroll 16
    for (int k = 0; k < 128; ++k) {
      float4 a = o4[k], bq = w4[k];
      acc += a.x * bq.x + a.y * bq.y + a.z * bq.z + a.w * bq.w;
    }
    em[row * TT + t] = acc + eb[t];
  }
}

// ---------------------------------------------------------------- K6: CRF NLL (32 independent batches)
__global__ __launch_bounds__(64) void k6_crf(
    const int* __restrict__ sentence, const int* __restrict__ tags,
    const float* __restrict__ em, const float* __restrict__ trans,
    const float* __restrict__ startv, const float* __restrict__ endv,
    float* __restrict__ outp) {
  int b = blockIdx.x;
  int j = threadIdx.x;
  __shared__ float ash[TT];
  __shared__ float red[TT];
  float tc[TT];
  float alpha = 0.f;
  if (j < TT) {
    #pragma unroll
    for (int i = 0; i < TT; ++i) tc[i] = trans[i * TT + j];
    alpha = startv[j] + em[(0 * BB + b) * TT + j];
  }
  for (int s = 1; s < SS; ++s) {
    if (j < TT) ash[j] = alpha;
    __syncthreads();
    int m = (sentence[s * BB + b] != 1) ? 1 : 0;
    if (j < TT) {
      float mx = -1e30f;
      #pragma unroll
      for (int i = 0; i < TT; ++i) mx = fmaxf(mx, ash[i] + tc[i]);
      float sum = 0.f;
      #pragma unroll
      for (int i = 0; i < TT; ++i) sum += __expf(ash[i] + tc[i] - mx);
      float nxt = mx + __logf(sum) + em[(s * BB + b) * TT + j];
      if (m) alpha = nxt;
    }
    __syncthreads();
  }
  if (j < TT) red[j] = alpha + endv[j];
  __syncthreads();
  if (j == 0) {
    float mx = -1e30f;
    for (int i = 0; i < TT; ++i) mx = fmaxf(mx, red[i]);
    float sum = 0.f;
    for (int i = 0; i < TT; ++i) sum += __expf(red[i] - mx);
    float den = mx + __logf(sum);
    int prev = tags[0 * BB + b];
    float num = startv[prev] + em[(0 * BB + b) * TT + prev];
    for (int s = 1; s < SS; ++s) {
      int tg = tags[s * BB + b];
      if (sentence[s * BB + b] != 1) {
        num += trans[prev * TT + tg] + em[(s * BB + b) * TT + tg];
        prev = tg;
      }
    }
    num += endv[prev];
    atomicAdd(outp, den - num);
  }
}

// ---------------------------------------------------------------- launcher
extern "C" void kernel_launch(void* const* d_in, const int* in_sizes, int n_in,
                              void* d_out, int out_size, void* d_ws, size_t ws_size,
                              hipStream_t stream) {
  (void)in_sizes; (void)n_in; (void)out_size; (void)ws_size;
  const int*   sentence = (const int*)d_in[0];
  const int*   charidx  = (const int*)d_in[1];
  const int*   tags     = (const int*)d_in[2];
  const float* Wwe   = (const float*)d_in[3];
  const float* Wce   = (const float*)d_in[4];
  const float* cWihF = (const float*)d_in[5];
  const float* cWhhF = (const float*)d_in[6];
  const float* cbF   = (const float*)d_in[7];
  const float* wWihF = (const float*)d_in[8];
  const float* wWhhF = (const float*)d_in[9];
  const float* wbF   = (const float*)d_in[10];
  const float* cWihB = (const float*)d_in[11];
  const float* cWhhB = (const float*)d_in[12];
  const float* cbB   = (const float*)d_in[13];
  const float* wWihB = (const float*)d_in[14];
  const float* wWhhB = (const float*)d_in[15];
  const float* wbB   = (const float*)d_in[16];
  const float* eW    = (const float*)d_in[17];
  const float* eb    = (const float*)d_in[18];
  const float* trans = (const float*)d_in[19];
  const float* startv= (const float*)d_in[20];
  const float* endv  = (const float*)d_in[21];

  char* ws = (char*)d_ws;
  float*          ihv   = (float*)(ws + 512);             //  204800 B
  float*          x     = (float*)(ws + 205312);          // 6291456 B
  float*          wg    = (float*)(ws + 6496768);         // 33554432 B
  float*          outh  = (float*)(ws + 40116736);        // 8388608 B
  float*          em    = (float*)(ws + 48505344);        //  278528 B
  // hbuf (131072 B) aliases the head of the em region: em is written only by
  // k5 (after k4 completes), so the tagged h-exchange buffer is dead by then.
  unsigned int*   hbuf  = (unsigned int*)(ws + 48505344);
  // total ws usage: 48,783,872 B (unchanged)

  hipMemsetAsync(hbuf, 0, 131072, stream);   // stale tags never match 1..128
  hipMemsetAsync(d_out, 0, sizeof(float), stream);

  k0_ihvocab<<<200, 256, 0, stream>>>(Wce, cWihF, cbF, cWihB, cbB, ihv);
  k1_char<<<512, 256, 0, stream>>>(charidx, cWhhF, cWhhB, ihv, x);
  k2_we<<<4096, 64, 0, stream>>>(sentence, Wwe, x);
  k3_ihgemm<<<dim3(16, 32), 256, 0, stream>>>(x, wWihF, wbF, wWihB, wbB, wg);
  k4_word<<<32, 64, 0, stream>>>(wWhhF, wWhhB, wg, outh, hbuf);
  k5_emit<<<4096, 64, 0, stream>>>(outh, eW, eb, em);
  k6_crf<<<32, 64, 0, stream>>>(sentence, tags, em, trans, startv, endv, (float*)d_out);
}